// Round 8
// baseline (398.508 us; speedup 1.0000x reference)
//
#include <hip/hip_runtime.h>
#include <math.h>

#define TOKENS  32768
#define HIDDEN  2048
#define EXPERTS 64
#define TOPK    8
#define TB      32                // tokens per block
#define BK      64                // k per staged window
#define NWIN    (HIDDEN / BK)     // 32

// ---------------------------------------------------------------------------
// Kernel 1: W[64][2048] -> wT[2048][64] (d_ws): per-k expert weights become
// consecutive, so a lane reads wT[k][e0..e0+8) as 2 float4 (8-way lane merge,
// L2-resident 512 KB).
// ---------------------------------------------------------------------------
__global__ void wt_transpose(const float* __restrict__ W, float* __restrict__ wT) {
    int i = blockIdx.x * 256 + threadIdx.x;   // 0..131071
    int k = i >> 6;
    int e = i & 63;
    wT[i] = W[e * HIDDEN + k];
}

// ---------------------------------------------------------------------------
// Kernel 2: fused router. 256 thr (4 waves) per 32-token group; 1024 blocks.
// Wave wv owns window rows [wv*16, wv*16+16) of each BK=64 A-window (K-split 4).
// Lane tile: 4 tokens x 8 experts (acc 32 VGPR).
//  - A: LDS window [64 k][32 t], double-buffered, swizzled col
//       c = 4*((t/4 + k/4)&7) + (t&3)  -> staging writes exactly 2-way (free),
//       compute reads = b128 8-address broadcast (free).
//  - W: global wT with 4-deep rolling register prefetch (use-distance ~280 cyc
//       > L2 latency) -- no LDS charging, 8-way lane merge.
// One barrier per window. Epilogue: 4-partial LDS reduce (stride-33, b32,
// 2-way banks) + bias, per-token top-8 + softmax + scatter, coalesced writes.
// launch_bounds arg2=1: arg2=4 empirically caps VGPR at 64 (r2/r4/r5) -> spill.
// ---------------------------------------------------------------------------
__global__ __launch_bounds__(256, 1)
void router_v7(const float* __restrict__ A,
               const float* __restrict__ wT,
               const float* __restrict__ bias,
               float* __restrict__ out) {
    __shared__ float smem[4608];   // staging 2x2048 | epi: red@0 (64*33), scat@2112 (32*65)
    const int tid  = threadIdx.x;
    const int wv   = tid >> 6;
    const int lane = tid & 63;
    const int g    = blockIdx.x;

    const int tg = lane & 7;       // token group: tokens tg*4..tg*4+3
    const int eg = lane >> 3;
    const int e0 = eg * 8;         // experts e0..e0+7

    // staging map: thread -> token row st, k-chunk sc (8 lanes cover 128 B of a row)
    const int st = tid >> 3;       // 0..31
    const int sc = tid & 7;        // k-offsets sc*4..sc*4+3 and 32+sc*4..+3
    const float* asrc = A + ((size_t)g * TB + st) * HIDDEN + sc * 4;
    // swizzled column for this thread's writes (same for both chunks, all j)
    const int wcol = 4 * (((st >> 2) + sc) & 7) + (st & 3);

    float* buf0 = smem;            // [64][32]
    float* buf1 = smem + 2048;

    float acc[4][8];
    #pragma unroll
    for (int i = 0; i < 4; ++i)
        #pragma unroll
        for (int j = 0; j < 8; ++j) acc[i][j] = 0.f;

    // ---- W rolling prefetch: 4 slots x 2 float4 ----
    float4 wq0[4], wq1[4];
    #pragma unroll
    for (int slot = 0; slot < 4; ++slot) {
        const float* p = wT + (size_t)(wv * 16 + slot) * 64;
        wq0[slot] = *(const float4*)(p + e0);
        wq1[slot] = *(const float4*)(p + e0 + 4);
    }

    // ---- stage window 0 ----
    {
        float4 a0 = *(const float4*)(asrc);
        float4 a1 = *(const float4*)(asrc + 32);
        buf0[(sc * 4 + 0) * 32 + wcol] = a0.x;
        buf0[(sc * 4 + 1) * 32 + wcol] = a0.y;
        buf0[(sc * 4 + 2) * 32 + wcol] = a0.z;
        buf0[(sc * 4 + 3) * 32 + wcol] = a0.w;
        buf0[(32 + sc * 4 + 0) * 32 + wcol] = a1.x;
        buf0[(32 + sc * 4 + 1) * 32 + wcol] = a1.y;
        buf0[(32 + sc * 4 + 2) * 32 + wcol] = a1.z;
        buf0[(32 + sc * 4 + 3) * 32 + wcol] = a1.w;
    }

    #pragma unroll 1
    for (int s = 0; s < NWIN; ++s) {
        float* cb = (s & 1) ? buf1 : buf0;
        float* nb = (s & 1) ? buf0 : buf1;
        __syncthreads();                       // cb published; nb free to overwrite

        float4 sa0, sa1;
        const bool more = (s + 1 < NWIN);
        if (more) {                            // in flight across the whole window
            sa0 = *(const float4*)(asrc + (s + 1) * BK);
            sa1 = *(const float4*)(asrc + (s + 1) * BK + 32);
        }

        #pragma unroll
        for (int kk = 0; kk < 16; ++kk) {
            const int krow = wv * 16 + kk;
            float4 av = *(const float4*)(cb + krow * 32 +
                                         4 * ((tg + wv * 4 + (kk >> 2)) & 7));
            const int slot = kk & 3;
            float4 w0 = wq0[slot], w1 = wq1[slot];
            // prefetch the k four iterations ahead (crossing into next window)
            int knext = (kk < 12) ? (s * BK + wv * 16 + kk + 4)
                                  : ((s + 1) * BK + wv * 16 + (kk - 12));
            if (knext < HIDDEN) {
                const float* p = wT + (size_t)knext * 64;
                wq0[slot] = *(const float4*)(p + e0);
                wq1[slot] = *(const float4*)(p + e0 + 4);
            }
            float a_[4]  = {av.x, av.y, av.z, av.w};
            float wl_[4] = {w0.x, w0.y, w0.z, w0.w};
            float wh_[4] = {w1.x, w1.y, w1.z, w1.w};
            #pragma unroll
            for (int i = 0; i < 4; ++i) {
                acc[i][0] = fmaf(a_[i], wl_[0], acc[i][0]);
                acc[i][1] = fmaf(a_[i], wl_[1], acc[i][1]);
                acc[i][2] = fmaf(a_[i], wl_[2], acc[i][2]);
                acc[i][3] = fmaf(a_[i], wl_[3], acc[i][3]);
                acc[i][4] = fmaf(a_[i], wh_[0], acc[i][4]);
                acc[i][5] = fmaf(a_[i], wh_[1], acc[i][5]);
                acc[i][6] = fmaf(a_[i], wh_[2], acc[i][6]);
                acc[i][7] = fmaf(a_[i], wh_[3], acc[i][7]);
            }
        }

        if (more) {                            // write next window after compute
            nb[(sc * 4 + 0) * 32 + wcol] = sa0.x;
            nb[(sc * 4 + 1) * 32 + wcol] = sa0.y;
            nb[(sc * 4 + 2) * 32 + wcol] = sa0.z;
            nb[(sc * 4 + 3) * 32 + wcol] = sa0.w;
            nb[(32 + sc * 4 + 0) * 32 + wcol] = sa1.x;
            nb[(32 + sc * 4 + 1) * 32 + wcol] = sa1.y;
            nb[(32 + sc * 4 + 2) * 32 + wcol] = sa1.z;
            nb[(32 + sc * 4 + 3) * 32 + wcol] = sa1.w;
        }
    }

    // ---- epilogue: reduce 4 partials, stride-33 rows (2-way banks, b32) ----
    float* red  = smem;            // [64 e][stride 33]
    float* scat = smem + 2112;     // [32 t][65]

    __syncthreads();               // staging dead; LDS reusable
    if (wv == 0) {
        #pragma unroll
        for (int j = 0; j < 8; ++j)
            #pragma unroll
            for (int i = 0; i < 4; ++i)
                red[(e0 + j) * 33 + tg * 4 + i] = acc[i][j];
    }
    for (int i = tid; i < TB * 65; i += 256) scat[i] = 0.f;
    __syncthreads();
    if (wv == 1) {
        #pragma unroll
        for (int j = 0; j < 8; ++j)
            #pragma unroll
            for (int i = 0; i < 4; ++i)
                red[(e0 + j) * 33 + tg * 4 + i] += acc[i][j];
    }
    __syncthreads();
    if (wv == 2) {
        #pragma unroll
        for (int j = 0; j < 8; ++j)
            #pragma unroll
            for (int i = 0; i < 4; ++i)
                red[(e0 + j) * 33 + tg * 4 + i] += acc[i][j];
    }
    __syncthreads();
    if (wv == 3) {                 // last partial + bias (exactly once per elem)
        #pragma unroll
        for (int j = 0; j < 8; ++j) {
            float b = bias[e0 + j];
            #pragma unroll
            for (int i = 0; i < 4; ++i)
                red[(e0 + j) * 33 + tg * 4 + i] += acc[i][j] + b;
        }
    }
    __syncthreads();

    // ---- top-8 + softmax + scatter: one thread per token ----
    if (tid < TB) {
        const int t = tid;
        float v[64];
        #pragma unroll
        for (int e = 0; e < 64; ++e) v[e] = red[e * 33 + t];

        float tvals[TOPK]; int tix[TOPK]; float probs[TOPK];
        unsigned long long chosen = 0ull;
        #pragma unroll
        for (int j = 0; j < TOPK; ++j) {
            float best = -INFINITY; int bi = 0;
            #pragma unroll
            for (int e = 0; e < 64; ++e) {
                bool ok = ((chosen >> e) & 1ull) == 0ull;
                if (ok && v[e] > best) { best = v[e]; bi = e; }  // strict >: lowest idx on tie
            }
            chosen |= (1ull << bi);
            tvals[j] = best; tix[j] = bi;
        }
        float m = tvals[0];
        float ssum = 0.f;
        #pragma unroll
        for (int j = 0; j < TOPK; ++j) { probs[j] = __expf(tvals[j] - m); ssum += probs[j]; }
        float inv = 1.f / ssum;
        #pragma unroll
        for (int j = 0; j < TOPK; ++j) probs[j] *= inv;

        #pragma unroll
        for (int j = 0; j < TOPK; ++j) scat[t * 65 + tix[j]] = probs[j];

        float* oidx = out + (size_t)TOKENS * EXPERTS;
        const int token = g * TB + t;
        #pragma unroll
        for (int j = 0; j < TOPK; ++j) oidx[(size_t)token * TOPK + j] = (float)tix[j];
    }
    __syncthreads();

    // ---- coalesced score write: 32 tokens x 64 experts = 512 float4 ----
    float* oscore = out + (size_t)g * (TB * 64);
    #pragma unroll
    for (int p = 0; p < 2; ++p) {
        int fi  = tid + 256 * p;        // float4 index 0..511
        int tok = fi >> 4;
        int es  = (fi & 15) * 4;
        float4 vv;
        vv.x = scat[tok * 65 + es + 0];
        vv.y = scat[tok * 65 + es + 1];
        vv.z = scat[tok * 65 + es + 2];
        vv.w = scat[tok * 65 + es + 3];
        *(float4*)(oscore + (size_t)fi * 4) = vv;
    }
}

extern "C" void kernel_launch(void* const* d_in, const int* in_sizes, int n_in,
                              void* d_out, int out_size, void* d_ws, size_t ws_size,
                              hipStream_t stream) {
    const float* A    = (const float*)d_in[0];   // [32768, 2048] fp32
    const float* W    = (const float*)d_in[1];   // [64, 2048] fp32
    const float* bias = (const float*)d_in[2];   // [64] fp32
    float* out = (float*)d_out;                  // scores (32768*64) ++ idx (32768*8)
    float* wT  = (float*)d_ws;                   // 512 KB scratch

    wt_transpose<<<512, 256, 0, stream>>>(W, wT);
    router_v7<<<TOKENS / TB, 256, 0, stream>>>(A, wT, bias, out);
}

// Round 9
// 64.839 us; speedup vs baseline: 6.1461x; 6.1461x over previous
//
#include <hip/hip_runtime.h>
#include <math.h>

typedef _Float16 half8 __attribute__((ext_vector_type(8)));
typedef _Float16 half4 __attribute__((ext_vector_type(4)));
typedef float    f32x4 __attribute__((ext_vector_type(4)));

#define TOKENS  32768
#define HIDDEN  2048
#define EXPERTS 64
#define TOPK    8
#define BKW     64               // k per staged window
#define NWIN    (HIDDEN / BKW)   // 32
#define LDH     72               // LDS row stride in halves (144 B: 16B-aligned, 2-way banks)

// ---------------------------------------------------------------------------
// Kernel 1: split W fp32 -> (Whi, Wlo) fp16, row-major [64][2048] in d_ws.
// ---------------------------------------------------------------------------
__global__ void wsplit(const float* __restrict__ W,
                       _Float16* __restrict__ whi, _Float16* __restrict__ wlo) {
    int i = blockIdx.x * 256 + threadIdx.x;     // 0..131071
    float w = W[i];
    _Float16 h = (_Float16)w;
    whi[i] = h;
    wlo[i] = (_Float16)(w - (float)h);
}

// ---------------------------------------------------------------------------
// Kernel 2: MFMA router via fp16x3 split (hi*hi + hi*lo + lo*hi, fp32 acc).
// Block = 256 thr (4 waves) owns 64 tokens x 64 experts x full K.
// Wave w: token slab [w*16, w*16+16), all 4 expert tiles (acc = 4 x f32x4).
// Per 64-k window: stage A (fp32->hi/lo fp16) and W (pre-split) into LDS
// (row-major, stride 144B), single-buffered with 2 barriers; next-window
// global loads fly during compute. Frags: A[t][k..k+7] / W[e][k..k+7] are
// 16B-contiguous -> ds_read_b128, no transpose anywhere.
// Epilogue: logits(+bias) -> LDS, per-token top-8 + softmax + scatter.
// ---------------------------------------------------------------------------
__global__ __launch_bounds__(256, 1)
void router_mfma(const float* __restrict__ A,
                 const _Float16* __restrict__ Wh,
                 const _Float16* __restrict__ Wl,
                 const float* __restrict__ bias,
                 float* __restrict__ out) {
    __shared__ __align__(16) _Float16 hsm[4 * 64 * LDH];   // Ahi|Alo|Whi|Wlo = 36864 B
    _Float16* Ahs = hsm;
    _Float16* Als = hsm + 64 * LDH;
    _Float16* Whs = hsm + 2 * 64 * LDH;
    _Float16* Wls = hsm + 3 * 64 * LDH;

    const int tid = threadIdx.x;
    const int w   = tid >> 6;          // wave = 16-token slab
    const int l   = tid & 63;
    const int g   = blockIdx.x;

    // A staging map: 4 rounds x (16 rows x 16 float4-chunks) -- coalesced
    const int s_tok = tid >> 4;        // 0..15
    const int s_c   = tid & 15;        // k-chunk: floats s_c*4..s_c*4+3
    // W staging map: thread -> expert row, two 16B chunks (wc, wc+4)
    const int we = tid >> 2;           // 0..63
    const int wc = tid & 3;

    const float* Abase = A + (size_t)g * 64 * HIDDEN;

    f32x4 acc[4];
    #pragma unroll
    for (int n = 0; n < 4; ++n) acc[n] = (f32x4){0.f, 0.f, 0.f, 0.f};

    float4 ar0, ar1, ar2, ar3;         // A staging regs (4 rows)
    half8 wrh0, wrh1, wrl0, wrl1;      // W staging regs

    #define LOADA(win) do {                                                  \
        const float* p_ = Abase + (size_t)(win) * BKW + s_c * 4;             \
        ar0 = *(const float4*)(p_ + (size_t)(s_tok     ) * HIDDEN);          \
        ar1 = *(const float4*)(p_ + (size_t)(s_tok + 16) * HIDDEN);          \
        ar2 = *(const float4*)(p_ + (size_t)(s_tok + 32) * HIDDEN);          \
        ar3 = *(const float4*)(p_ + (size_t)(s_tok + 48) * HIDDEN);          \
    } while (0)

    #define LOADW(win) do {                                                  \
        const _Float16* ph_ = Wh + (size_t)we * HIDDEN + (win) * BKW;        \
        const _Float16* pl_ = Wl + (size_t)we * HIDDEN + (win) * BKW;        \
        wrh0 = *(const half8*)(ph_ + wc * 8);                                \
        wrh1 = *(const half8*)(ph_ + wc * 8 + 32);                           \
        wrl0 = *(const half8*)(pl_ + wc * 8);                                \
        wrl1 = *(const half8*)(pl_ + wc * 8 + 32);                           \
    } while (0)

    #define STAGE1(v, trow) do {                                             \
        _Float16 h0_ = (_Float16)(v).x, h1_ = (_Float16)(v).y;               \
        _Float16 h2_ = (_Float16)(v).z, h3_ = (_Float16)(v).w;               \
        half4 hh_ = {h0_, h1_, h2_, h3_};                                    \
        half4 ll_ = {(_Float16)((v).x - (float)h0_),                         \
                     (_Float16)((v).y - (float)h1_),                         \
                     (_Float16)((v).z - (float)h2_),                         \
                     (_Float16)((v).w - (float)h3_)};                        \
        *(half4*)(&Ahs[(trow) * LDH + s_c * 4]) = hh_;                       \
        *(half4*)(&Als[(trow) * LDH + s_c * 4]) = ll_;                       \
    } while (0)

    LOADA(0);
    LOADW(0);

    #pragma unroll 1
    for (int win = 0; win < NWIN; ++win) {
        __syncthreads();                       // previous window fully consumed
        STAGE1(ar0, s_tok);
        STAGE1(ar1, s_tok + 16);
        STAGE1(ar2, s_tok + 32);
        STAGE1(ar3, s_tok + 48);
        *(half8*)(&Whs[we * LDH + wc * 8])      = wrh0;
        *(half8*)(&Whs[we * LDH + wc * 8 + 32]) = wrh1;
        *(half8*)(&Wls[we * LDH + wc * 8])      = wrl0;
        *(half8*)(&Wls[we * LDH + wc * 8 + 32]) = wrl1;
        __syncthreads();                       // window published

        if (win + 1 < NWIN) {                  // next-window loads fly during MFMA
            LOADA(win + 1);
            LOADW(win + 1);
        }

        #pragma unroll
        for (int ks = 0; ks < 2; ++ks) {
            const int ko = ks * 32 + (l >> 4) * 8;
            half8 ahi = *(const half8*)(&Ahs[(w * 16 + (l & 15)) * LDH + ko]);
            half8 alo = *(const half8*)(&Als[(w * 16 + (l & 15)) * LDH + ko]);
            #pragma unroll
            for (int n = 0; n < 4; ++n) {
                half8 bh = *(const half8*)(&Whs[(n * 16 + (l & 15)) * LDH + ko]);
                half8 bl = *(const half8*)(&Wls[(n * 16 + (l & 15)) * LDH + ko]);
                acc[n] = __builtin_amdgcn_mfma_f32_16x16x32_f16(ahi, bh, acc[n], 0, 0, 0);
                acc[n] = __builtin_amdgcn_mfma_f32_16x16x32_f16(ahi, bl, acc[n], 0, 0, 0);
                acc[n] = __builtin_amdgcn_mfma_f32_16x16x32_f16(alo, bh, acc[n], 0, 0, 0);
            }
        }
    }
    #undef LOADA
    #undef LOADW
    #undef STAGE1

    // ---- epilogue: logits (+bias) to LDS, top-8 + softmax + scatter ----
    __syncthreads();                           // staging LDS dead; alias as float
    float* lg = (float*)hsm;                   // [64 tok][68]
    float* sc = (float*)hsm + 64 * 68;         // [64 tok][65]

    // D layout (m89, dtype-independent): col = lane&15, row = (lane>>4)*4 + q
    #pragma unroll
    for (int n = 0; n < 4; ++n) {
        float b = bias[n * 16 + (l & 15)];
        #pragma unroll
        for (int q = 0; q < 4; ++q) {
            int trow = w * 16 + (l >> 4) * 4 + q;
            lg[trow * 68 + n * 16 + (l & 15)] = acc[n][q] + b;
        }
    }
    for (int i = tid; i < 64 * 65; i += 256) sc[i] = 0.f;
    __syncthreads();

    if (tid < 64) {
        const int t = tid;
        float v[64];
        #pragma unroll
        for (int e = 0; e < 64; ++e) v[e] = lg[t * 68 + e];

        float tvals[TOPK]; int tix[TOPK]; float probs[TOPK];
        unsigned long long chosen = 0ull;
        #pragma unroll
        for (int j = 0; j < TOPK; ++j) {
            float best = -INFINITY; int bi = 0;
            #pragma unroll
            for (int e = 0; e < 64; ++e) {
                bool ok = ((chosen >> e) & 1ull) == 0ull;
                if (ok && v[e] > best) { best = v[e]; bi = e; }  // strict >: lowest idx on tie
            }
            chosen |= (1ull << bi);
            tvals[j] = best; tix[j] = bi;
        }
        float m = tvals[0];
        float ssum = 0.f;
        #pragma unroll
        for (int j = 0; j < TOPK; ++j) { probs[j] = __expf(tvals[j] - m); ssum += probs[j]; }
        float inv = 1.f / ssum;
        #pragma unroll
        for (int j = 0; j < TOPK; ++j) probs[j] *= inv;

        #pragma unroll
        for (int j = 0; j < TOPK; ++j) sc[t * 65 + tix[j]] = probs[j];

        float* oidx = out + (size_t)TOKENS * EXPERTS;
        const int token = g * 64 + t;
        #pragma unroll
        for (int j = 0; j < TOPK; ++j) oidx[(size_t)token * TOPK + j] = (float)tix[j];
    }
    __syncthreads();

    // ---- coalesced score write: 64 tokens x 64 experts = 1024 float4 ----
    float* oscore = out + (size_t)g * 4096;
    #pragma unroll
    for (int p = 0; p < 4; ++p) {
        int fi  = tid + 256 * p;               // float4 index 0..1023
        int tok = fi >> 4;
        int es  = (fi & 15) * 4;
        float4 vv;
        vv.x = sc[tok * 65 + es + 0];
        vv.y = sc[tok * 65 + es + 1];
        vv.z = sc[tok * 65 + es + 2];
        vv.w = sc[tok * 65 + es + 3];
        *(float4*)(oscore + (size_t)fi * 4) = vv;
    }
}

extern "C" void kernel_launch(void* const* d_in, const int* in_sizes, int n_in,
                              void* d_out, int out_size, void* d_ws, size_t ws_size,
                              hipStream_t stream) {
    const float* A    = (const float*)d_in[0];   // [32768, 2048] fp32
    const float* W    = (const float*)d_in[1];   // [64, 2048] fp32
    const float* bias = (const float*)d_in[2];   // [64] fp32
    float* out = (float*)d_out;                  // scores (32768*64) ++ idx (32768*8)

    _Float16* whi = (_Float16*)d_ws;             // 256 KB
    _Float16* wlo = whi + EXPERTS * HIDDEN;      // 256 KB

    wsplit<<<512, 256, 0, stream>>>(W, whi, wlo);
    router_mfma<<<TOKENS / 64, 256, 0, stream>>>(A, whi, wlo, bias, out);
}